// Round 9
// baseline (561.876 us; speedup 1.0000x reference)
//
#include <hip/hip_runtime.h>
#include <stdint.h>
#include <stddef.h>

#define N_NODES 100000
#define N_EDGES 6400000
#define HIDDEN 16
#define NBKT 782          /* ceil(100000/128) coarse buckets of 128 nodes */
#define CAP 8704          /* bucket region capacity: mean 8184 + 5.7 sigma */
#define P1_EPB 8192       /* edges per part1 block */

__host__ __device__ inline uint32_t rotl32(uint32_t x, int n) {
    return (x << n) | (x >> (32 - n));
}

// Exact JAX threefry2x32 (20 rounds)
__host__ __device__ inline void threefry2x32(uint32_t k0, uint32_t k1,
                                             uint32_t x0, uint32_t x1,
                                             uint32_t& o0, uint32_t& o1) {
    uint32_t k2 = k0 ^ k1 ^ 0x1BD11BDAu;
    x0 += k0; x1 += k1;
    x0 += x1; x1 = rotl32(x1, 13); x1 ^= x0;
    x0 += x1; x1 = rotl32(x1, 15); x1 ^= x0;
    x0 += x1; x1 = rotl32(x1, 26); x1 ^= x0;
    x0 += x1; x1 = rotl32(x1,  6); x1 ^= x0;
    x0 += k1; x1 += k2 + 1u;
    x0 += x1; x1 = rotl32(x1, 17); x1 ^= x0;
    x0 += x1; x1 = rotl32(x1, 29); x1 ^= x0;
    x0 += x1; x1 = rotl32(x1, 16); x1 ^= x0;
    x0 += x1; x1 = rotl32(x1, 24); x1 ^= x0;
    x0 += k2; x1 += k0 + 2u;
    x0 += x1; x1 = rotl32(x1, 13); x1 ^= x0;
    x0 += x1; x1 = rotl32(x1, 15); x1 ^= x0;
    x0 += x1; x1 = rotl32(x1, 26); x1 ^= x0;
    x0 += x1; x1 = rotl32(x1,  6); x1 ^= x0;
    x0 += k0; x1 += k1 + 3u;
    x0 += x1; x1 = rotl32(x1, 17); x1 ^= x0;
    x0 += x1; x1 = rotl32(x1, 29); x1 ^= x0;
    x0 += x1; x1 = rotl32(x1, 16); x1 ^= x0;
    x0 += x1; x1 = rotl32(x1, 24); x1 ^= x0;
    x0 += k1; x1 += k2 + 4u;
    x0 += x1; x1 = rotl32(x1, 13); x1 ^= x0;
    x0 += x1; x1 = rotl32(x1, 15); x1 ^= x0;
    x0 += x1; x1 = rotl32(x1, 26); x1 ^= x0;
    x0 += x1; x1 = rotl32(x1,  6); x1 ^= x0;
    x0 += k2; x1 += k0 + 5u;
    o0 = x0; o1 = x1;
}

// jax_threefry_partitionable: bits(j) = a^b of threefry(key, 0, j)
__device__ inline float apply_dropout(float v, uint32_t flat, uint32_t k0, uint32_t k1) {
    uint32_t a, b;
    threefry2x32(k0, k1, 0u, flat, a, b);
    uint32_t bits = a ^ b;
    float u = __uint_as_float((bits >> 9) | 0x3F800000u) - 1.0f;
    return (u >= 0.3f) ? v * (1.0f / 0.7f) : 0.0f;
}

// ---- gcursor[b] = b*CAP (fixed-capacity bucket regions, no scan) ---------
__global__ void initcur_kernel(int* __restrict__ gcursor) {
    int b = threadIdx.x;
    if (b < NBKT) gcursor[b] = b * CAP;
}

// ---- partition v2: LDS-staged counting sort + coalesced run flush --------
// Per block: histogram 782 buckets -> in-block scan -> place sorted into
// LDS -> one wave per bucket bursts the run to buf (lines written once).
__global__ __launch_bounds__(256) void part1_kernel(const int* __restrict__ src,
                                                    const int* __restrict__ dst,
                                                    int* __restrict__ gcursor,
                                                    int* __restrict__ buf) {
    __shared__ int lhist[NBKT], lbase[NBKT], lstart[NBKT], lcur[NBKT];
    __shared__ int pscan[256];
    __shared__ int lsort[P1_EPB];
    int tid = threadIdx.x;
    size_t base = (size_t)blockIdx.x * P1_EPB;
    for (int b = tid; b < NBKT; b += 256) lhist[b] = 0;
    __syncthreads();
    // phase 1: histogram (32 edges/thread)
    for (int i = 0; i < 32; i++) {
        size_t e = base + (size_t)i * 256 + tid;
        if (e < N_EDGES) atomicAdd(&lhist[dst[e] >> 7], 1);
    }
    __syncthreads();
    // phase 2: exclusive scan over 782 counters (4 per thread + HS on 256)
    int local[4], run = 0;
    #pragma unroll
    for (int j = 0; j < 4; j++) {
        int idx = tid * 4 + j;
        local[j] = run;
        run += (idx < NBKT) ? lhist[idx] : 0;
    }
    pscan[tid] = run;
    __syncthreads();
    #pragma unroll
    for (int o = 1; o < 256; o <<= 1) {
        int t2 = (tid >= o) ? pscan[tid - o] : 0;
        __syncthreads();
        pscan[tid] += t2;
        __syncthreads();
    }
    int prev = (tid > 0) ? pscan[tid - 1] : 0;
    #pragma unroll
    for (int j = 0; j < 4; j++) {
        int idx = tid * 4 + j;
        if (idx < NBKT) { lstart[idx] = prev + local[j]; lcur[idx] = prev + local[j]; }
    }
    __syncthreads();
    // phase 3: reserve global run bases
    for (int b = tid; b < NBKT; b += 256) {
        int c = lhist[b];
        lbase[b] = c ? atomicAdd(&gcursor[b], c) : 0;
    }
    __syncthreads();
    // phase 4: place packed words sorted by bucket into LDS
    for (int i = 0; i < 32; i++) {
        size_t e = base + (size_t)i * 256 + tid;
        if (e < N_EDGES) {
            int d = dst[e], s = src[e];
            int b = d >> 7;
            int p = atomicAdd(&lcur[b], 1);
            lsort[p] = ((d & 127) << 17) | s;
        }
    }
    __syncthreads();
    // phase 5: burst-flush each run coalesced (one wave per bucket)
    int wv = tid >> 6, ln = tid & 63;
    for (int b = wv; b < NBKT; b += 4) {
        int st = lstart[b], c = lhist[b], gb = lbase[b];
        int lim = (b + 1) * CAP;
        for (int k = ln; k < c; k += 64) {
            int pos = gb + k;
            if (pos < lim)   // capacity guard (P ~ 5e-6 total)
                buf[pos] = lsort[st + k];
        }
    }
}

// ---- part2: per-bucket fine sort in LDS, in place; emits nodeinfo+dinv ---
// nodeinfo[n] = (deg << 23) | start_index_into_buf
__global__ __launch_bounds__(256) void part2_kernel(const int* __restrict__ gcursor,
                                                    int* __restrict__ buf,
                                                    int* __restrict__ nodeinfo,
                                                    float* __restrict__ dinv) {
    __shared__ int lcnt[128], lcur[128];
    __shared__ int lsort[CAP];
    int b = blockIdx.x, tid = threadIdx.x;
    int base = b * CAP;
    int end = gcursor[b];
    int count = end - base;
    if (tid < 128) lcnt[tid] = 0;
    __syncthreads();
    for (int i = tid; i < count; i += 256)
        atomicAdd(&lcnt[buf[base + i] >> 17], 1);
    __syncthreads();
    int v = (tid < 128) ? lcnt[tid] : 0;
    #pragma unroll
    for (int o = 1; o < 128; o <<= 1) {
        int t2 = (tid < 128 && tid >= o) ? lcnt[tid - o] : 0;
        __syncthreads();
        if (tid < 128 && tid >= o) lcnt[tid] += t2;
        __syncthreads();
    }
    if (tid < 128) {
        int excl = lcnt[tid] - v;
        lcur[tid] = excl;
        int n = b * 128 + tid;
        if (n < N_NODES) {
            nodeinfo[n] = (v << 23) | (base + excl);
            dinv[n] = rsqrtf((float)v + 1.0f);  // +1 self-loop
        }
    }
    __syncthreads();
    for (int i = tid; i < count; i += 256) {
        int w = buf[base + i];
        int pos = atomicAdd(&lcur[w >> 17], 1);
        lsort[pos] = w & 0x1FFFF;
    }
    __syncthreads();
    for (int i = tid; i < count; i += 256) buf[base + i] = lsort[i];
}

// ---- LayerNorm + W1 + pre-scale by dinv (one wave per node) --------------
__global__ void ln_w1_kernel(const float* __restrict__ x,
                             const float* __restrict__ gamma,
                             const float* __restrict__ beta,
                             const float* __restrict__ W1,
                             const float* __restrict__ dinv,
                             float* __restrict__ g1) {
    int wave = (blockIdx.x * blockDim.x + threadIdx.x) >> 6;
    int lane = threadIdx.x & 63;
    if (wave >= N_NODES) return;
    const float* xr = x + (size_t)wave * 128;
    float x0 = xr[lane], x1 = xr[lane + 64];

    float s = x0 + x1;
    #pragma unroll
    for (int o = 32; o; o >>= 1) s += __shfl_xor(s, o, 64);
    float mu = s * (1.0f / 128.0f);
    float d0 = x0 - mu, d1 = x1 - mu;
    float v = d0 * d0 + d1 * d1;
    #pragma unroll
    for (int o = 32; o; o >>= 1) v += __shfl_xor(v, o, 64);
    float rstd = rsqrtf(v * (1.0f / 128.0f) + 1e-5f);
    float xn0 = d0 * rstd * gamma[lane] + beta[lane];
    float xn1 = d1 * rstd * gamma[lane + 64] + beta[lane + 64];

    float p[HIDDEN];
    const float* wr0 = W1 + (size_t)lane * HIDDEN;
    const float* wr1 = W1 + (size_t)(lane + 64) * HIDDEN;
    #pragma unroll
    for (int j = 0; j < HIDDEN; j++) p[j] = xn0 * wr0[j] + xn1 * wr1[j];
    #pragma unroll
    for (int o = 32; o; o >>= 1) {
        #pragma unroll
        for (int j = 0; j < HIDDEN; j++) p[j] += __shfl_xor(p[j], o, 64);
    }
    if (lane < HIDDEN) g1[(size_t)wave * HIDDEN + lane] = p[lane] * dinv[wave];
}

// ---- pull conv1 + fused finalize1 (one wave per node, float4 gathers) ----
__global__ __launch_bounds__(256) void pull1_kernel(const int* __restrict__ nodeinfo,
                             const int* __restrict__ sorted_src,
                             const float* __restrict__ g1,
                             const float* __restrict__ dinv,
                             const float* __restrict__ b1,
                             const float* __restrict__ W2,
                             float* __restrict__ g2,
                             uint32_t k0, uint32_t k1) {
    __shared__ float sW2[HIDDEN * HIDDEN];
    if (threadIdx.x < HIDDEN * HIDDEN) sW2[threadIdx.x] = W2[threadIdx.x];
    __syncthreads();
    int n = blockIdx.x * 4 + (threadIdx.x >> 6);   // grid*4 == N_NODES exactly
    int lane = threadIdx.x & 63;
    int c = lane & 3, e4 = lane >> 2;
    int info = nodeinfo[n];
    int start = info & 0x7FFFFF;
    int end = start + (int)((unsigned)info >> 23);

    float4 acc = make_float4(0.f, 0.f, 0.f, 0.f);
    if (e4 == 0) acc = *(const float4*)&g1[(size_t)n * HIDDEN + c * 4];  // self
    for (int kb = start; kb < end; kb += 64) {
        int e = kb + lane;
        int idx = (e < end) ? sorted_src[e] : -1;
        #pragma unroll
        for (int t = 0; t < 4; t++) {
            int s = __shfl(idx, t * 16 + e4, 64);
            if (s >= 0) {
                const float4 gv = *(const float4*)&g1[(size_t)s * HIDDEN + c * 4];
                acc.x += gv.x; acc.y += gv.y; acc.z += gv.z; acc.w += gv.w;
            }
        }
    }
    #pragma unroll
    for (int o = 4; o < 64; o <<= 1) {
        acc.x += __shfl_xor(acc.x, o, 64);
        acc.y += __shfl_xor(acc.y, o, 64);
        acc.z += __shfl_xor(acc.z, o, 64);
        acc.w += __shfl_xor(acc.w, o, 64);
    }
    float di = dinv[n];
    const float4 b1c = *(const float4*)&b1[c * 4];
    uint32_t fb = (uint32_t)(n * HIDDEN + c * 4);
    float h[4];
    h[0] = apply_dropout(fmaxf(di * acc.x + b1c.x, 0.f), fb + 0, k0, k1);
    h[1] = apply_dropout(fmaxf(di * acc.y + b1c.y, 0.f), fb + 1, k0, k1);
    h[2] = apply_dropout(fmaxf(di * acc.z + b1c.z, 0.f), fb + 2, k0, k1);
    h[3] = apply_dropout(fmaxf(di * acc.w + b1c.w, 0.f), fb + 3, k0, k1);
    float4 o4 = make_float4(0.f, 0.f, 0.f, 0.f);
    #pragma unroll
    for (int i = 0; i < HIDDEN; i++) {
        float hi = __shfl(h[i & 3], i >> 2, 64);
        const float4 w = *(const float4*)&sW2[i * HIDDEN + c * 4];
        o4.x += hi * w.x; o4.y += hi * w.y; o4.z += hi * w.z; o4.w += hi * w.w;
    }
    if (e4 == 0)
        *(float4*)&g2[(size_t)n * HIDDEN + c * 4] =
            make_float4(o4.x * di, o4.y * di, o4.z * di, o4.w * di);
}

// ---- pull conv2 + fused finalize2 ----------------------------------------
__global__ __launch_bounds__(256) void pull2_kernel(const int* __restrict__ nodeinfo,
                             const int* __restrict__ sorted_src,
                             const float* __restrict__ g2,
                             const float* __restrict__ dinv,
                             const float* __restrict__ b2,
                             float* __restrict__ out,
                             uint32_t k0, uint32_t k1) {
    int n = blockIdx.x * 4 + (threadIdx.x >> 6);
    int lane = threadIdx.x & 63;
    int c = lane & 3, e4 = lane >> 2;
    int info = nodeinfo[n];
    int start = info & 0x7FFFFF;
    int end = start + (int)((unsigned)info >> 23);

    float4 acc = make_float4(0.f, 0.f, 0.f, 0.f);
    if (e4 == 0) acc = *(const float4*)&g2[(size_t)n * HIDDEN + c * 4];
    for (int kb = start; kb < end; kb += 64) {
        int e = kb + lane;
        int idx = (e < end) ? sorted_src[e] : -1;
        #pragma unroll
        for (int t = 0; t < 4; t++) {
            int s = __shfl(idx, t * 16 + e4, 64);
            if (s >= 0) {
                const float4 gv = *(const float4*)&g2[(size_t)s * HIDDEN + c * 4];
                acc.x += gv.x; acc.y += gv.y; acc.z += gv.z; acc.w += gv.w;
            }
        }
    }
    #pragma unroll
    for (int o = 4; o < 64; o <<= 1) {
        acc.x += __shfl_xor(acc.x, o, 64);
        acc.y += __shfl_xor(acc.y, o, 64);
        acc.z += __shfl_xor(acc.z, o, 64);
        acc.w += __shfl_xor(acc.w, o, 64);
    }
    if (e4 == 0) {
        float di = dinv[n];
        const float4 b2c = *(const float4*)&b2[c * 4];
        uint32_t fb = (uint32_t)(n * HIDDEN + c * 4);
        float4 r;
        r.x = apply_dropout(fmaxf(di * acc.x + b2c.x, 0.f), fb + 0, k0, k1);
        r.y = apply_dropout(fmaxf(di * acc.y + b2c.y, 0.f), fb + 1, k0, k1);
        r.z = apply_dropout(fmaxf(di * acc.z + b2c.z, 0.f), fb + 2, k0, k1);
        r.w = apply_dropout(fmaxf(di * acc.w + b2c.w, 0.f), fb + 3, k0, k1);
        *(float4*)&out[(size_t)n * HIDDEN + c * 4] = r;
    }
}

extern "C" void kernel_launch(void* const* d_in, const int* in_sizes, int n_in,
                              void* d_out, int out_size, void* d_ws, size_t ws_size,
                              hipStream_t stream) {
    const float* x     = (const float*)d_in[0];
    const int*   ei    = (const int*)d_in[1];
    const float* gamma = (const float*)d_in[2];
    const float* beta  = (const float*)d_in[3];
    const float* W1    = (const float*)d_in[4];
    const float* b1    = (const float*)d_in[5];
    const float* W2    = (const float*)d_in[6];
    const float* b2    = (const float*)d_in[7];
    float* out = (float*)d_out;
    const int* src = ei;
    const int* dst = ei + N_EDGES;

    uint32_t dk1_0, dk1_1, dk2_0, dk2_1;
    threefry2x32(0u, 42u, 0u, 0u, dk1_0, dk1_1);
    threefry2x32(0u, 42u, 0u, 1u, dk2_0, dk2_1);

    // ws layout (4B elems): gcursor[1024] | nodeinfo[100k] | dinv[100k] |
    // buf[NBKT*CAP] | g1[1.6M] | g2[1.6M]   (~41 MB)
    int*   gcursor  = (int*)d_ws;
    int*   nodeinfo = gcursor + 1024;
    float* dinv     = (float*)(nodeinfo + N_NODES);
    int*   buf      = (int*)(dinv + N_NODES);
    float* g1       = (float*)(buf + (size_t)NBKT * CAP);
    float* g2       = g1 + (size_t)N_NODES * HIDDEN;

    const int NB_W  = N_NODES / 4;                     // 25000 (4 waves/block)
    const int NB_P1 = (N_EDGES + P1_EPB - 1) / P1_EPB; // 782

    initcur_kernel<<<1, 1024, 0, stream>>>(gcursor);
    part1_kernel<<<NB_P1, 256, 0, stream>>>(src, dst, gcursor, buf);
    part2_kernel<<<NBKT, 256, 0, stream>>>(gcursor, buf, nodeinfo, dinv);
    ln_w1_kernel<<<NB_W, 256, 0, stream>>>(x, gamma, beta, W1, dinv, g1);
    pull1_kernel<<<NB_W, 256, 0, stream>>>(nodeinfo, buf, g1,
                                           dinv, b1, W2, g2, dk1_0, dk1_1);
    pull2_kernel<<<NB_W, 256, 0, stream>>>(nodeinfo, buf, g2,
                                           dinv, b2, out, dk2_0, dk2_1);
}

// Round 10
// 480.008 us; speedup vs baseline: 1.1706x; 1.1706x over previous
//
#include <hip/hip_runtime.h>
#include <stdint.h>
#include <stddef.h>

#define N_NODES 100000
#define N_EDGES 6400000
#define HIDDEN 16
#define NBKT 782          /* ceil(100000/128) coarse buckets of 128 nodes */
#define CAP 8704          /* bucket region capacity: mean 8184 + 5.7 sigma */
#define P1_EPB 8192       /* edges per part1 block */

__host__ __device__ inline uint32_t rotl32(uint32_t x, int n) {
    return (x << n) | (x >> (32 - n));
}

// Exact JAX threefry2x32 (20 rounds)
__host__ __device__ inline void threefry2x32(uint32_t k0, uint32_t k1,
                                             uint32_t x0, uint32_t x1,
                                             uint32_t& o0, uint32_t& o1) {
    uint32_t k2 = k0 ^ k1 ^ 0x1BD11BDAu;
    x0 += k0; x1 += k1;
    x0 += x1; x1 = rotl32(x1, 13); x1 ^= x0;
    x0 += x1; x1 = rotl32(x1, 15); x1 ^= x0;
    x0 += x1; x1 = rotl32(x1, 26); x1 ^= x0;
    x0 += x1; x1 = rotl32(x1,  6); x1 ^= x0;
    x0 += k1; x1 += k2 + 1u;
    x0 += x1; x1 = rotl32(x1, 17); x1 ^= x0;
    x0 += x1; x1 = rotl32(x1, 29); x1 ^= x0;
    x0 += x1; x1 = rotl32(x1, 16); x1 ^= x0;
    x0 += x1; x1 = rotl32(x1, 24); x1 ^= x0;
    x0 += k2; x1 += k0 + 2u;
    x0 += x1; x1 = rotl32(x1, 13); x1 ^= x0;
    x0 += x1; x1 = rotl32(x1, 15); x1 ^= x0;
    x0 += x1; x1 = rotl32(x1, 26); x1 ^= x0;
    x0 += x1; x1 = rotl32(x1,  6); x1 ^= x0;
    x0 += k0; x1 += k1 + 3u;
    x0 += x1; x1 = rotl32(x1, 17); x1 ^= x0;
    x0 += x1; x1 = rotl32(x1, 29); x1 ^= x0;
    x0 += x1; x1 = rotl32(x1, 16); x1 ^= x0;
    x0 += x1; x1 = rotl32(x1, 24); x1 ^= x0;
    x0 += k1; x1 += k2 + 4u;
    x0 += x1; x1 = rotl32(x1, 13); x1 ^= x0;
    x0 += x1; x1 = rotl32(x1, 15); x1 ^= x0;
    x0 += x1; x1 = rotl32(x1, 26); x1 ^= x0;
    x0 += x1; x1 = rotl32(x1,  6); x1 ^= x0;
    x0 += k2; x1 += k0 + 5u;
    o0 = x0; o1 = x1;
}

// jax_threefry_partitionable: bits(j) = a^b of threefry(key, 0, j)
__device__ inline float apply_dropout(float v, uint32_t flat, uint32_t k0, uint32_t k1) {
    uint32_t a, b;
    threefry2x32(k0, k1, 0u, flat, a, b);
    uint32_t bits = a ^ b;
    float u = __uint_as_float((bits >> 9) | 0x3F800000u) - 1.0f;
    return (u >= 0.3f) ? v * (1.0f / 0.7f) : 0.0f;
}

// ---- gcursor[b] = b*CAP (fixed-capacity bucket regions, no scan) ---------
__global__ void initcur_kernel(int* __restrict__ gcursor) {
    int b = threadIdx.x;
    if (b < NBKT) gcursor[b] = b * CAP;
}

// ---- partition: LDS-staged counting sort + 16-lane-group run flush -------
// 512 threads for latency hiding (3 blocks/CU via LDS -> 24 waves/CU).
__global__ __launch_bounds__(512) void part1_kernel(const int* __restrict__ src,
                                                    const int* __restrict__ dst,
                                                    int* __restrict__ gcursor,
                                                    int* __restrict__ buf) {
    __shared__ int lhist[NBKT], lbase[NBKT], lstart[NBKT], lcur[NBKT];
    __shared__ int pscan[512];
    __shared__ int lsort[P1_EPB];
    int tid = threadIdx.x;
    size_t base = (size_t)blockIdx.x * P1_EPB;
    for (int b = tid; b < NBKT; b += 512) lhist[b] = 0;
    __syncthreads();
    // phase 1: histogram (16 edges/thread)
    for (int i = 0; i < 16; i++) {
        size_t e = base + (size_t)i * 512 + tid;
        if (e < N_EDGES) atomicAdd(&lhist[dst[e] >> 7], 1);
    }
    __syncthreads();
    // phase 2: exclusive scan over 782 counters (2/thread + HS on 512)
    int i0 = tid * 2, i1 = tid * 2 + 1;
    int c0 = (i0 < NBKT) ? lhist[i0] : 0;
    int c1 = (i1 < NBKT) ? lhist[i1] : 0;
    pscan[tid] = c0 + c1;
    __syncthreads();
    #pragma unroll
    for (int o = 1; o < 512; o <<= 1) {
        int t2 = (tid >= o) ? pscan[tid - o] : 0;
        __syncthreads();
        pscan[tid] += t2;
        __syncthreads();
    }
    int prev = (tid > 0) ? pscan[tid - 1] : 0;
    if (i0 < NBKT) { lstart[i0] = prev;      lcur[i0] = prev; }
    if (i1 < NBKT) { lstart[i1] = prev + c0; lcur[i1] = prev + c0; }
    __syncthreads();
    // phase 3: reserve global run bases
    for (int b = tid; b < NBKT; b += 512) {
        int c = lhist[b];
        lbase[b] = c ? atomicAdd(&gcursor[b], c) : 0;
    }
    __syncthreads();
    // phase 4: place packed words sorted by bucket into LDS
    for (int i = 0; i < 16; i++) {
        size_t e = base + (size_t)i * 512 + tid;
        if (e < N_EDGES) {
            int d = dst[e], s = src[e];
            int b = d >> 7;
            int p = atomicAdd(&lcur[b], 1);
            lsort[p] = ((d & 127) << 17) | s;
        }
    }
    __syncthreads();
    // phase 5: flush runs, one 16-lane group per bucket (runs avg ~10.5)
    int grp = tid >> 4, gl = tid & 15;
    for (int b = grp; b < NBKT; b += 32) {
        int st = lstart[b], c = lhist[b], gb = lbase[b];
        int lim = (b + 1) * CAP;
        for (int k = gl; k < c; k += 16) {
            int pos = gb + k;
            if (pos < lim)   // capacity guard (P ~ 5e-6 total)
                buf[pos] = lsort[st + k];
        }
    }
}

// ---- part2: per-bucket fine sort in LDS, in place; emits nodeinfo+dinv ---
// nodeinfo[n] = (deg << 23) | start_index_into_buf
__global__ __launch_bounds__(512) void part2_kernel(const int* __restrict__ gcursor,
                                                    int* __restrict__ buf,
                                                    int* __restrict__ nodeinfo,
                                                    float* __restrict__ dinv) {
    __shared__ int lcnt[128], lcur[128];
    __shared__ int lsort[CAP];
    int b = blockIdx.x, tid = threadIdx.x;
    int base = b * CAP;
    int end = gcursor[b];
    int count = end - base;
    if (tid < 128) lcnt[tid] = 0;
    __syncthreads();
    for (int i = tid; i < count; i += 512)
        atomicAdd(&lcnt[buf[base + i] >> 17], 1);
    __syncthreads();
    int v = (tid < 128) ? lcnt[tid] : 0;
    #pragma unroll
    for (int o = 1; o < 128; o <<= 1) {
        int t2 = (tid < 128 && tid >= o) ? lcnt[tid - o] : 0;
        __syncthreads();
        if (tid < 128 && tid >= o) lcnt[tid] += t2;
        __syncthreads();
    }
    if (tid < 128) {
        int excl = lcnt[tid] - v;
        lcur[tid] = excl;
        int n = b * 128 + tid;
        if (n < N_NODES) {
            nodeinfo[n] = (v << 23) | (base + excl);
            dinv[n] = rsqrtf((float)v + 1.0f);  // +1 self-loop
        }
    }
    __syncthreads();
    for (int i = tid; i < count; i += 512) {
        int w = buf[base + i];
        int pos = atomicAdd(&lcur[w >> 17], 1);
        lsort[pos] = w & 0x1FFFF;
    }
    __syncthreads();
    for (int i = tid; i < count; i += 512) buf[base + i] = lsort[i];
}

// ---- LayerNorm + W1 + pre-scale by dinv (one wave per node) --------------
__global__ void ln_w1_kernel(const float* __restrict__ x,
                             const float* __restrict__ gamma,
                             const float* __restrict__ beta,
                             const float* __restrict__ W1,
                             const float* __restrict__ dinv,
                             float* __restrict__ g1) {
    int wave = (blockIdx.x * blockDim.x + threadIdx.x) >> 6;
    int lane = threadIdx.x & 63;
    if (wave >= N_NODES) return;
    const float* xr = x + (size_t)wave * 128;
    float x0 = xr[lane], x1 = xr[lane + 64];

    float s = x0 + x1;
    #pragma unroll
    for (int o = 32; o; o >>= 1) s += __shfl_xor(s, o, 64);
    float mu = s * (1.0f / 128.0f);
    float d0 = x0 - mu, d1 = x1 - mu;
    float v = d0 * d0 + d1 * d1;
    #pragma unroll
    for (int o = 32; o; o >>= 1) v += __shfl_xor(v, o, 64);
    float rstd = rsqrtf(v * (1.0f / 128.0f) + 1e-5f);
    float xn0 = d0 * rstd * gamma[lane] + beta[lane];
    float xn1 = d1 * rstd * gamma[lane + 64] + beta[lane + 64];

    float p[HIDDEN];
    const float* wr0 = W1 + (size_t)lane * HIDDEN;
    const float* wr1 = W1 + (size_t)(lane + 64) * HIDDEN;
    #pragma unroll
    for (int j = 0; j < HIDDEN; j++) p[j] = xn0 * wr0[j] + xn1 * wr1[j];
    #pragma unroll
    for (int o = 32; o; o >>= 1) {
        #pragma unroll
        for (int j = 0; j < HIDDEN; j++) p[j] += __shfl_xor(p[j], o, 64);
    }
    if (lane < HIDDEN) g1[(size_t)wave * HIDDEN + lane] = p[lane] * dinv[wave];
}

// ---- pull conv1 + fused finalize1 (one wave per node, float4 gathers) ----
__global__ __launch_bounds__(256) void pull1_kernel(const int* __restrict__ nodeinfo,
                             const int* __restrict__ sorted_src,
                             const float* __restrict__ g1,
                             const float* __restrict__ dinv,
                             const float* __restrict__ b1,
                             const float* __restrict__ W2,
                             float* __restrict__ g2,
                             uint32_t k0, uint32_t k1) {
    __shared__ float sW2[HIDDEN * HIDDEN];
    if (threadIdx.x < HIDDEN * HIDDEN) sW2[threadIdx.x] = W2[threadIdx.x];
    __syncthreads();
    int n = blockIdx.x * 4 + (threadIdx.x >> 6);   // grid*4 == N_NODES exactly
    int lane = threadIdx.x & 63;
    int c = lane & 3, e4 = lane >> 2;
    int info = nodeinfo[n];
    int start = info & 0x7FFFFF;
    int end = start + (int)((unsigned)info >> 23);

    float4 acc = make_float4(0.f, 0.f, 0.f, 0.f);
    if (e4 == 0) acc = *(const float4*)&g1[(size_t)n * HIDDEN + c * 4];  // self
    for (int kb = start; kb < end; kb += 64) {
        int e = kb + lane;
        int idx = (e < end) ? sorted_src[e] : -1;
        #pragma unroll
        for (int t = 0; t < 4; t++) {
            int s = __shfl(idx, t * 16 + e4, 64);
            if (s >= 0) {
                const float4 gv = *(const float4*)&g1[(size_t)s * HIDDEN + c * 4];
                acc.x += gv.x; acc.y += gv.y; acc.z += gv.z; acc.w += gv.w;
            }
        }
    }
    #pragma unroll
    for (int o = 4; o < 64; o <<= 1) {
        acc.x += __shfl_xor(acc.x, o, 64);
        acc.y += __shfl_xor(acc.y, o, 64);
        acc.z += __shfl_xor(acc.z, o, 64);
        acc.w += __shfl_xor(acc.w, o, 64);
    }
    float di = dinv[n];
    const float4 b1c = *(const float4*)&b1[c * 4];
    uint32_t fb = (uint32_t)(n * HIDDEN + c * 4);
    float h[4];
    h[0] = apply_dropout(fmaxf(di * acc.x + b1c.x, 0.f), fb + 0, k0, k1);
    h[1] = apply_dropout(fmaxf(di * acc.y + b1c.y, 0.f), fb + 1, k0, k1);
    h[2] = apply_dropout(fmaxf(di * acc.z + b1c.z, 0.f), fb + 2, k0, k1);
    h[3] = apply_dropout(fmaxf(di * acc.w + b1c.w, 0.f), fb + 3, k0, k1);
    float4 o4 = make_float4(0.f, 0.f, 0.f, 0.f);
    #pragma unroll
    for (int i = 0; i < HIDDEN; i++) {
        float hi = __shfl(h[i & 3], i >> 2, 64);
        const float4 w = *(const float4*)&sW2[i * HIDDEN + c * 4];
        o4.x += hi * w.x; o4.y += hi * w.y; o4.z += hi * w.z; o4.w += hi * w.w;
    }
    if (e4 == 0)
        *(float4*)&g2[(size_t)n * HIDDEN + c * 4] =
            make_float4(o4.x * di, o4.y * di, o4.z * di, o4.w * di);
}

// ---- pull conv2 + fused finalize2 ----------------------------------------
__global__ __launch_bounds__(256) void pull2_kernel(const int* __restrict__ nodeinfo,
                             const int* __restrict__ sorted_src,
                             const float* __restrict__ g2,
                             const float* __restrict__ dinv,
                             const float* __restrict__ b2,
                             float* __restrict__ out,
                             uint32_t k0, uint32_t k1) {
    int n = blockIdx.x * 4 + (threadIdx.x >> 6);
    int lane = threadIdx.x & 63;
    int c = lane & 3, e4 = lane >> 2;
    int info = nodeinfo[n];
    int start = info & 0x7FFFFF;
    int end = start + (int)((unsigned)info >> 23);

    float4 acc = make_float4(0.f, 0.f, 0.f, 0.f);
    if (e4 == 0) acc = *(const float4*)&g2[(size_t)n * HIDDEN + c * 4];
    for (int kb = start; kb < end; kb += 64) {
        int e = kb + lane;
        int idx = (e < end) ? sorted_src[e] : -1;
        #pragma unroll
        for (int t = 0; t < 4; t++) {
            int s = __shfl(idx, t * 16 + e4, 64);
            if (s >= 0) {
                const float4 gv = *(const float4*)&g2[(size_t)s * HIDDEN + c * 4];
                acc.x += gv.x; acc.y += gv.y; acc.z += gv.z; acc.w += gv.w;
            }
        }
    }
    #pragma unroll
    for (int o = 4; o < 64; o <<= 1) {
        acc.x += __shfl_xor(acc.x, o, 64);
        acc.y += __shfl_xor(acc.y, o, 64);
        acc.z += __shfl_xor(acc.z, o, 64);
        acc.w += __shfl_xor(acc.w, o, 64);
    }
    if (e4 == 0) {
        float di = dinv[n];
        const float4 b2c = *(const float4*)&b2[c * 4];
        uint32_t fb = (uint32_t)(n * HIDDEN + c * 4);
        float4 r;
        r.x = apply_dropout(fmaxf(di * acc.x + b2c.x, 0.f), fb + 0, k0, k1);
        r.y = apply_dropout(fmaxf(di * acc.y + b2c.y, 0.f), fb + 1, k0, k1);
        r.z = apply_dropout(fmaxf(di * acc.z + b2c.z, 0.f), fb + 2, k0, k1);
        r.w = apply_dropout(fmaxf(di * acc.w + b2c.w, 0.f), fb + 3, k0, k1);
        *(float4*)&out[(size_t)n * HIDDEN + c * 4] = r;
    }
}

extern "C" void kernel_launch(void* const* d_in, const int* in_sizes, int n_in,
                              void* d_out, int out_size, void* d_ws, size_t ws_size,
                              hipStream_t stream) {
    const float* x     = (const float*)d_in[0];
    const int*   ei    = (const int*)d_in[1];
    const float* gamma = (const float*)d_in[2];
    const float* beta  = (const float*)d_in[3];
    const float* W1    = (const float*)d_in[4];
    const float* b1    = (const float*)d_in[5];
    const float* W2    = (const float*)d_in[6];
    const float* b2    = (const float*)d_in[7];
    float* out = (float*)d_out;
    const int* src = ei;
    const int* dst = ei + N_EDGES;

    uint32_t dk1_0, dk1_1, dk2_0, dk2_1;
    threefry2x32(0u, 42u, 0u, 0u, dk1_0, dk1_1);
    threefry2x32(0u, 42u, 0u, 1u, dk2_0, dk2_1);

    // ws layout (4B elems): gcursor[1024] | nodeinfo[100k] | dinv[100k] |
    // buf[NBKT*CAP] | g1[1.6M] | g2[1.6M]   (~41 MB)
    int*   gcursor  = (int*)d_ws;
    int*   nodeinfo = gcursor + 1024;
    float* dinv     = (float*)(nodeinfo + N_NODES);
    int*   buf      = (int*)(dinv + N_NODES);
    float* g1       = (float*)(buf + (size_t)NBKT * CAP);
    float* g2       = g1 + (size_t)N_NODES * HIDDEN;

    const int NB_W  = N_NODES / 4;                     // 25000 (4 waves/block)
    const int NB_P1 = (N_EDGES + P1_EPB - 1) / P1_EPB; // 782

    initcur_kernel<<<1, 1024, 0, stream>>>(gcursor);
    part1_kernel<<<NB_P1, 512, 0, stream>>>(src, dst, gcursor, buf);
    part2_kernel<<<NBKT, 512, 0, stream>>>(gcursor, buf, nodeinfo, dinv);
    ln_w1_kernel<<<NB_W, 256, 0, stream>>>(x, gamma, beta, W1, dinv, g1);
    pull1_kernel<<<NB_W, 256, 0, stream>>>(nodeinfo, buf, g1,
                                           dinv, b1, W2, g2, dk1_0, dk1_1);
    pull2_kernel<<<NB_W, 256, 0, stream>>>(nodeinfo, buf, g2,
                                           dinv, b2, out, dk2_0, dk2_1);
}

// Round 11
// 421.143 us; speedup vs baseline: 1.3342x; 1.1398x over previous
//
#include <hip/hip_runtime.h>
#include <stdint.h>
#include <stddef.h>

#define N_NODES 100000
#define N_EDGES 6400000
#define HIDDEN 16
#define NBKT 782          /* ceil(100000/128) coarse buckets of 128 nodes */
#define CAP 8704          /* bucket region capacity: mean 8184 + 5.7 sigma */
#define P1_EPB 8192       /* edges per part1 block */

__host__ __device__ inline uint32_t rotl32(uint32_t x, int n) {
    return (x << n) | (x >> (32 - n));
}

// Exact JAX threefry2x32 (20 rounds)
__host__ __device__ inline void threefry2x32(uint32_t k0, uint32_t k1,
                                             uint32_t x0, uint32_t x1,
                                             uint32_t& o0, uint32_t& o1) {
    uint32_t k2 = k0 ^ k1 ^ 0x1BD11BDAu;
    x0 += k0; x1 += k1;
    x0 += x1; x1 = rotl32(x1, 13); x1 ^= x0;
    x0 += x1; x1 = rotl32(x1, 15); x1 ^= x0;
    x0 += x1; x1 = rotl32(x1, 26); x1 ^= x0;
    x0 += x1; x1 = rotl32(x1,  6); x1 ^= x0;
    x0 += k1; x1 += k2 + 1u;
    x0 += x1; x1 = rotl32(x1, 17); x1 ^= x0;
    x0 += x1; x1 = rotl32(x1, 29); x1 ^= x0;
    x0 += x1; x1 = rotl32(x1, 16); x1 ^= x0;
    x0 += x1; x1 = rotl32(x1, 24); x1 ^= x0;
    x0 += k2; x1 += k0 + 2u;
    x0 += x1; x1 = rotl32(x1, 13); x1 ^= x0;
    x0 += x1; x1 = rotl32(x1, 15); x1 ^= x0;
    x0 += x1; x1 = rotl32(x1, 26); x1 ^= x0;
    x0 += x1; x1 = rotl32(x1,  6); x1 ^= x0;
    x0 += k0; x1 += k1 + 3u;
    x0 += x1; x1 = rotl32(x1, 17); x1 ^= x0;
    x0 += x1; x1 = rotl32(x1, 29); x1 ^= x0;
    x0 += x1; x1 = rotl32(x1, 16); x1 ^= x0;
    x0 += x1; x1 = rotl32(x1, 24); x1 ^= x0;
    x0 += k1; x1 += k2 + 4u;
    x0 += x1; x1 = rotl32(x1, 13); x1 ^= x0;
    x0 += x1; x1 = rotl32(x1, 15); x1 ^= x0;
    x0 += x1; x1 = rotl32(x1, 26); x1 ^= x0;
    x0 += x1; x1 = rotl32(x1,  6); x1 ^= x0;
    x0 += k2; x1 += k0 + 5u;
    o0 = x0; o1 = x1;
}

// jax_threefry_partitionable: bits(j) = a^b of threefry(key, 0, j)
__device__ inline float apply_dropout(float v, uint32_t flat, uint32_t k0, uint32_t k1) {
    uint32_t a, b;
    threefry2x32(k0, k1, 0u, flat, a, b);
    uint32_t bits = a ^ b;
    float u = __uint_as_float((bits >> 9) | 0x3F800000u) - 1.0f;
    return (u >= 0.3f) ? v * (1.0f / 0.7f) : 0.0f;
}

// ---- gcursor[b] = b*CAP (fixed-capacity bucket regions, no scan) ---------
__global__ void initcur_kernel(int* __restrict__ gcursor) {
    int b = threadIdx.x;
    if (b < NBKT) gcursor[b] = b * CAP;
}

// ---- partition: LDS-staged counting sort + 16-lane-group run flush -------
__global__ __launch_bounds__(512) void part1_kernel(const int* __restrict__ src,
                                                    const int* __restrict__ dst,
                                                    int* __restrict__ gcursor,
                                                    int* __restrict__ buf) {
    __shared__ int lhist[NBKT], lbase[NBKT], lstart[NBKT], lcur[NBKT];
    __shared__ int pscan[512];
    __shared__ int lsort[P1_EPB];
    int tid = threadIdx.x;
    size_t base = (size_t)blockIdx.x * P1_EPB;
    for (int b = tid; b < NBKT; b += 512) lhist[b] = 0;
    __syncthreads();
    for (int i = 0; i < 16; i++) {
        size_t e = base + (size_t)i * 512 + tid;
        if (e < N_EDGES) atomicAdd(&lhist[dst[e] >> 7], 1);
    }
    __syncthreads();
    int i0 = tid * 2, i1 = tid * 2 + 1;
    int c0 = (i0 < NBKT) ? lhist[i0] : 0;
    int c1 = (i1 < NBKT) ? lhist[i1] : 0;
    pscan[tid] = c0 + c1;
    __syncthreads();
    #pragma unroll
    for (int o = 1; o < 512; o <<= 1) {
        int t2 = (tid >= o) ? pscan[tid - o] : 0;
        __syncthreads();
        pscan[tid] += t2;
        __syncthreads();
    }
    int prev = (tid > 0) ? pscan[tid - 1] : 0;
    if (i0 < NBKT) { lstart[i0] = prev;      lcur[i0] = prev; }
    if (i1 < NBKT) { lstart[i1] = prev + c0; lcur[i1] = prev + c0; }
    __syncthreads();
    for (int b = tid; b < NBKT; b += 512) {
        int c = lhist[b];
        lbase[b] = c ? atomicAdd(&gcursor[b], c) : 0;
    }
    __syncthreads();
    for (int i = 0; i < 16; i++) {
        size_t e = base + (size_t)i * 512 + tid;
        if (e < N_EDGES) {
            int d = dst[e], s = src[e];
            int b = d >> 7;
            int p = atomicAdd(&lcur[b], 1);
            lsort[p] = ((d & 127) << 17) | s;
        }
    }
    __syncthreads();
    int grp = tid >> 4, gl = tid & 15;
    for (int b = grp; b < NBKT; b += 32) {
        int st = lstart[b], c = lhist[b], gb = lbase[b];
        int lim = (b + 1) * CAP;
        for (int k = gl; k < c; k += 16) {
            int pos = gb + k;
            if (pos < lim)   // capacity guard (P ~ 5e-6 total)
                buf[pos] = lsort[st + k];
        }
    }
}

// ---- part2: per-bucket fine sort in LDS, in place; emits nodeinfo+dinv ---
__global__ __launch_bounds__(512) void part2_kernel(const int* __restrict__ gcursor,
                                                    int* __restrict__ buf,
                                                    int* __restrict__ nodeinfo,
                                                    float* __restrict__ dinv) {
    __shared__ int lcnt[128], lcur[128];
    __shared__ int lsort[CAP];
    int b = blockIdx.x, tid = threadIdx.x;
    int base = b * CAP;
    int end = gcursor[b];
    int count = end - base;
    if (tid < 128) lcnt[tid] = 0;
    __syncthreads();
    for (int i = tid; i < count; i += 512)
        atomicAdd(&lcnt[buf[base + i] >> 17], 1);
    __syncthreads();
    int v = (tid < 128) ? lcnt[tid] : 0;
    #pragma unroll
    for (int o = 1; o < 128; o <<= 1) {
        int t2 = (tid < 128 && tid >= o) ? lcnt[tid - o] : 0;
        __syncthreads();
        if (tid < 128 && tid >= o) lcnt[tid] += t2;
        __syncthreads();
    }
    if (tid < 128) {
        int excl = lcnt[tid] - v;
        lcur[tid] = excl;
        int n = b * 128 + tid;
        if (n < N_NODES) {
            nodeinfo[n] = (v << 23) | (base + excl);
            dinv[n] = rsqrtf((float)v + 1.0f);  // +1 self-loop
        }
    }
    __syncthreads();
    for (int i = tid; i < count; i += 512) {
        int w = buf[base + i];
        int pos = atomicAdd(&lcur[w >> 17], 1);
        lsort[pos] = w & 0x1FFFF;
    }
    __syncthreads();
    for (int i = tid; i < count; i += 512) buf[base + i] = lsort[i];
}

// ---- LayerNorm + W1 + pre-scale by dinv (one wave per node) --------------
// DS-lean: LN stats via sum/sumsq in one 6-round pass (12 shfl); p-reduce
// via vector-halving butterfly (17 shfl, feature = bitrev4(lane&15)).
__global__ void ln_w1_kernel(const float* __restrict__ x,
                             const float* __restrict__ gamma,
                             const float* __restrict__ beta,
                             const float* __restrict__ W1,
                             const float* __restrict__ dinv,
                             float* __restrict__ g1) {
    int wave = (blockIdx.x * blockDim.x + threadIdx.x) >> 6;
    int lane = threadIdx.x & 63;
    if (wave >= N_NODES) return;
    const float* xr = x + (size_t)wave * 128;
    float x0 = xr[lane], x1 = xr[lane + 64];

    // LN stats: reduce (sum, sumsq) together
    float s1 = x0 + x1;
    float s2 = x0 * x0 + x1 * x1;
    #pragma unroll
    for (int o = 32; o; o >>= 1) {
        s1 += __shfl_xor(s1, o, 64);
        s2 += __shfl_xor(s2, o, 64);
    }
    float mu = s1 * (1.0f / 128.0f);
    float var = s2 * (1.0f / 128.0f) - mu * mu;
    float rstd = rsqrtf(var + 1e-5f);
    float xn0 = (x0 - mu) * rstd * gamma[lane] + beta[lane];
    float xn1 = (x1 - mu) * rstd * gamma[lane + 64] + beta[lane + 64];

    float p[16];
    const float* wr0 = W1 + (size_t)lane * HIDDEN;
    const float* wr1 = W1 + (size_t)(lane + 64) * HIDDEN;
    #pragma unroll
    for (int j = 0; j < 16; j++) p[j] = xn0 * wr0[j] + xn1 * wr1[j];

    // vector-halving butterfly: rounds xor 1,2,4,8 halve the live vector
    float q[8];
    {
        int sel = lane & 1;
        #pragma unroll
        for (int j = 0; j < 8; j++) {
            float mine = sel ? p[j + 8] : p[j];
            float give = sel ? p[j] : p[j + 8];
            q[j] = mine + __shfl_xor(give, 1, 64);
        }
    }
    float r[4];
    {
        int sel = (lane >> 1) & 1;
        #pragma unroll
        for (int j = 0; j < 4; j++) {
            float mine = sel ? q[j + 4] : q[j];
            float give = sel ? q[j] : q[j + 4];
            r[j] = mine + __shfl_xor(give, 2, 64);
        }
    }
    float s[2];
    {
        int sel = (lane >> 2) & 1;
        #pragma unroll
        for (int j = 0; j < 2; j++) {
            float mine = sel ? r[j + 2] : r[j];
            float give = sel ? r[j] : r[j + 2];
            s[j] = mine + __shfl_xor(give, 4, 64);
        }
    }
    float t;
    {
        int sel = (lane >> 3) & 1;
        float mine = sel ? s[1] : s[0];
        float give = sel ? s[0] : s[1];
        t = mine + __shfl_xor(give, 8, 64);
    }
    t += __shfl_xor(t, 16, 64);
    t += __shfl_xor(t, 32, 64);

    if (lane < 16) {
        int f = ((lane & 1) << 3) | ((lane & 2) << 1) |
                ((lane & 4) >> 1) | ((lane & 8) >> 3);  // bitrev4
        g1[(size_t)wave * HIDDEN + f] = t * dinv[wave];
    }
}

// ---- pull conv1 + fused finalize1 (one wave per node, float4 gathers) ----
__global__ __launch_bounds__(256) void pull1_kernel(const int* __restrict__ nodeinfo,
                             const int* __restrict__ sorted_src,
                             const float* __restrict__ g1,
                             const float* __restrict__ dinv,
                             const float* __restrict__ b1,
                             const float* __restrict__ W2,
                             float* __restrict__ g2,
                             uint32_t k0, uint32_t k1) {
    __shared__ float sW2[HIDDEN * HIDDEN];
    if (threadIdx.x < HIDDEN * HIDDEN) sW2[threadIdx.x] = W2[threadIdx.x];
    __syncthreads();
    int n = blockIdx.x * 4 + (threadIdx.x >> 6);   // grid*4 == N_NODES exactly
    int lane = threadIdx.x & 63;
    int c = lane & 3, e4 = lane >> 2;
    int info = nodeinfo[n];
    int start = info & 0x7FFFFF;
    int end = start + (int)((unsigned)info >> 23);

    float4 acc = make_float4(0.f, 0.f, 0.f, 0.f);
    if (e4 == 0) acc = *(const float4*)&g1[(size_t)n * HIDDEN + c * 4];  // self
    for (int kb = start; kb < end; kb += 64) {
        int e = kb + lane;
        int idx = (e < end) ? sorted_src[e] : -1;
        #pragma unroll
        for (int t = 0; t < 4; t++) {
            int s = __shfl(idx, t * 16 + e4, 64);
            if (s >= 0) {
                const float4 gv = *(const float4*)&g1[(size_t)s * HIDDEN + c * 4];
                acc.x += gv.x; acc.y += gv.y; acc.z += gv.z; acc.w += gv.w;
            }
        }
    }
    #pragma unroll
    for (int o = 4; o < 64; o <<= 1) {
        acc.x += __shfl_xor(acc.x, o, 64);
        acc.y += __shfl_xor(acc.y, o, 64);
        acc.z += __shfl_xor(acc.z, o, 64);
        acc.w += __shfl_xor(acc.w, o, 64);
    }
    float di = dinv[n];
    const float4 b1c = *(const float4*)&b1[c * 4];
    uint32_t fb = (uint32_t)(n * HIDDEN + c * 4);
    float h[4];
    h[0] = apply_dropout(fmaxf(di * acc.x + b1c.x, 0.f), fb + 0, k0, k1);
    h[1] = apply_dropout(fmaxf(di * acc.y + b1c.y, 0.f), fb + 1, k0, k1);
    h[2] = apply_dropout(fmaxf(di * acc.z + b1c.z, 0.f), fb + 2, k0, k1);
    h[3] = apply_dropout(fmaxf(di * acc.w + b1c.w, 0.f), fb + 3, k0, k1);
    float4 o4 = make_float4(0.f, 0.f, 0.f, 0.f);
    #pragma unroll
    for (int i = 0; i < HIDDEN; i++) {
        float hi = __shfl(h[i & 3], i >> 2, 64);
        const float4 w = *(const float4*)&sW2[i * HIDDEN + c * 4];
        o4.x += hi * w.x; o4.y += hi * w.y; o4.z += hi * w.z; o4.w += hi * w.w;
    }
    if (e4 == 0)
        *(float4*)&g2[(size_t)n * HIDDEN + c * 4] =
            make_float4(o4.x * di, o4.y * di, o4.z * di, o4.w * di);
}

// ---- pull conv2 + fused finalize2 ----------------------------------------
__global__ __launch_bounds__(256) void pull2_kernel(const int* __restrict__ nodeinfo,
                             const int* __restrict__ sorted_src,
                             const float* __restrict__ g2,
                             const float* __restrict__ dinv,
                             const float* __restrict__ b2,
                             float* __restrict__ out,
                             uint32_t k0, uint32_t k1) {
    int n = blockIdx.x * 4 + (threadIdx.x >> 6);
    int lane = threadIdx.x & 63;
    int c = lane & 3, e4 = lane >> 2;
    int info = nodeinfo[n];
    int start = info & 0x7FFFFF;
    int end = start + (int)((unsigned)info >> 23);

    float4 acc = make_float4(0.f, 0.f, 0.f, 0.f);
    if (e4 == 0) acc = *(const float4*)&g2[(size_t)n * HIDDEN + c * 4];
    for (int kb = start; kb < end; kb += 64) {
        int e = kb + lane;
        int idx = (e < end) ? sorted_src[e] : -1;
        #pragma unroll
        for (int t = 0; t < 4; t++) {
            int s = __shfl(idx, t * 16 + e4, 64);
            if (s >= 0) {
                const float4 gv = *(const float4*)&g2[(size_t)s * HIDDEN + c * 4];
                acc.x += gv.x; acc.y += gv.y; acc.z += gv.z; acc.w += gv.w;
            }
        }
    }
    #pragma unroll
    for (int o = 4; o < 64; o <<= 1) {
        acc.x += __shfl_xor(acc.x, o, 64);
        acc.y += __shfl_xor(acc.y, o, 64);
        acc.z += __shfl_xor(acc.z, o, 64);
        acc.w += __shfl_xor(acc.w, o, 64);
    }
    if (e4 == 0) {
        float di = dinv[n];
        const float4 b2c = *(const float4*)&b2[c * 4];
        uint32_t fb = (uint32_t)(n * HIDDEN + c * 4);
        float4 r;
        r.x = apply_dropout(fmaxf(di * acc.x + b2c.x, 0.f), fb + 0, k0, k1);
        r.y = apply_dropout(fmaxf(di * acc.y + b2c.y, 0.f), fb + 1, k0, k1);
        r.z = apply_dropout(fmaxf(di * acc.z + b2c.z, 0.f), fb + 2, k0, k1);
        r.w = apply_dropout(fmaxf(di * acc.w + b2c.w, 0.f), fb + 3, k0, k1);
        *(float4*)&out[(size_t)n * HIDDEN + c * 4] = r;
    }
}

extern "C" void kernel_launch(void* const* d_in, const int* in_sizes, int n_in,
                              void* d_out, int out_size, void* d_ws, size_t ws_size,
                              hipStream_t stream) {
    const float* x     = (const float*)d_in[0];
    const int*   ei    = (const int*)d_in[1];
    const float* gamma = (const float*)d_in[2];
    const float* beta  = (const float*)d_in[3];
    const float* W1    = (const float*)d_in[4];
    const float* b1    = (const float*)d_in[5];
    const float* W2    = (const float*)d_in[6];
    const float* b2    = (const float*)d_in[7];
    float* out = (float*)d_out;
    const int* src = ei;
    const int* dst = ei + N_EDGES;

    uint32_t dk1_0, dk1_1, dk2_0, dk2_1;
    threefry2x32(0u, 42u, 0u, 0u, dk1_0, dk1_1);
    threefry2x32(0u, 42u, 0u, 1u, dk2_0, dk2_1);

    // ws layout (4B elems): gcursor[1024] | nodeinfo[100k] | dinv[100k] |
    // buf[NBKT*CAP] | g1[1.6M] | g2[1.6M]   (~41 MB)
    int*   gcursor  = (int*)d_ws;
    int*   nodeinfo = gcursor + 1024;
    float* dinv     = (float*)(nodeinfo + N_NODES);
    int*   buf      = (int*)(dinv + N_NODES);
    float* g1       = (float*)(buf + (size_t)NBKT * CAP);
    float* g2       = g1 + (size_t)N_NODES * HIDDEN;

    const int NB_W  = N_NODES / 4;                     // 25000 (4 waves/block)
    const int NB_P1 = (N_EDGES + P1_EPB - 1) / P1_EPB; // 782

    initcur_kernel<<<1, 1024, 0, stream>>>(gcursor);
    part1_kernel<<<NB_P1, 512, 0, stream>>>(src, dst, gcursor, buf);
    part2_kernel<<<NBKT, 512, 0, stream>>>(gcursor, buf, nodeinfo, dinv);
    ln_w1_kernel<<<NB_W, 256, 0, stream>>>(x, gamma, beta, W1, dinv, g1);
    pull1_kernel<<<NB_W, 256, 0, stream>>>(nodeinfo, buf, g1,
                                           dinv, b1, W2, g2, dk1_0, dk1_1);
    pull2_kernel<<<NB_W, 256, 0, stream>>>(nodeinfo, buf, g2,
                                           dinv, b2, out, dk2_0, dk2_1);
}

// Round 12
// 381.656 us; speedup vs baseline: 1.4722x; 1.1035x over previous
//
#include <hip/hip_runtime.h>
#include <stdint.h>
#include <stddef.h>

#define N_NODES 100000
#define N_EDGES 6400000
#define HIDDEN 16
#define NBKT 782          /* ceil(100000/128) coarse buckets of 128 nodes */
#define CAP 8704          /* bucket region capacity: mean 8184 + 5.7 sigma */
#define P1_EPB 8192       /* edges per part1 block */
#define NMASK 1600000     /* N_NODES*HIDDEN */

__host__ __device__ inline uint32_t rotl32(uint32_t x, int n) {
    return (x << n) | (x >> (32 - n));
}

// Exact JAX threefry2x32 (20 rounds)
__host__ __device__ inline void threefry2x32(uint32_t k0, uint32_t k1,
                                             uint32_t x0, uint32_t x1,
                                             uint32_t& o0, uint32_t& o1) {
    uint32_t k2 = k0 ^ k1 ^ 0x1BD11BDAu;
    x0 += k0; x1 += k1;
    x0 += x1; x1 = rotl32(x1, 13); x1 ^= x0;
    x0 += x1; x1 = rotl32(x1, 15); x1 ^= x0;
    x0 += x1; x1 = rotl32(x1, 26); x1 ^= x0;
    x0 += x1; x1 = rotl32(x1,  6); x1 ^= x0;
    x0 += k1; x1 += k2 + 1u;
    x0 += x1; x1 = rotl32(x1, 17); x1 ^= x0;
    x0 += x1; x1 = rotl32(x1, 29); x1 ^= x0;
    x0 += x1; x1 = rotl32(x1, 16); x1 ^= x0;
    x0 += x1; x1 = rotl32(x1, 24); x1 ^= x0;
    x0 += k2; x1 += k0 + 2u;
    x0 += x1; x1 = rotl32(x1, 13); x1 ^= x0;
    x0 += x1; x1 = rotl32(x1, 15); x1 ^= x0;
    x0 += x1; x1 = rotl32(x1, 26); x1 ^= x0;
    x0 += x1; x1 = rotl32(x1,  6); x1 ^= x0;
    x0 += k0; x1 += k1 + 3u;
    x0 += x1; x1 = rotl32(x1, 17); x1 ^= x0;
    x0 += x1; x1 = rotl32(x1, 29); x1 ^= x0;
    x0 += x1; x1 = rotl32(x1, 16); x1 ^= x0;
    x0 += x1; x1 = rotl32(x1, 24); x1 ^= x0;
    x0 += k1; x1 += k2 + 4u;
    x0 += x1; x1 = rotl32(x1, 13); x1 ^= x0;
    x0 += x1; x1 = rotl32(x1, 15); x1 ^= x0;
    x0 += x1; x1 = rotl32(x1, 26); x1 ^= x0;
    x0 += x1; x1 = rotl32(x1,  6); x1 ^= x0;
    x0 += k2; x1 += k0 + 5u;
    o0 = x0; o1 = x1;
}

// ---- dropout keep-bit masks, 1 threefry eval per lane, ballot-packed -----
__global__ __launch_bounds__(256) void dropmask_kernel(uint64_t* __restrict__ m1,
                                                       uint64_t* __restrict__ m2,
                                                       uint32_t k10, uint32_t k11,
                                                       uint32_t k20, uint32_t k21) {
    int g = blockIdx.x * blockDim.x + threadIdx.x;   // [0, 2*NMASK)
    int lane = threadIdx.x & 63;
    bool first = g < NMASK;
    uint32_t j = first ? (uint32_t)g : (uint32_t)(g - NMASK);
    uint32_t a, b;
    threefry2x32(first ? k10 : k20, first ? k11 : k21, 0u, j, a, b);
    uint32_t bits = a ^ b;
    float u = __uint_as_float((bits >> 9) | 0x3F800000u) - 1.0f;
    unsigned long long m = __ballot(u >= 0.3f);
    if (lane == 0) {
        int gw = g >> 6;
        if (first) m1[gw] = m;
        else       m2[gw - (NMASK >> 6)] = m;
    }
}

// ---- gcursor[b] = b*CAP (fixed-capacity bucket regions, no scan) ---------
__global__ void initcur_kernel(int* __restrict__ gcursor) {
    int b = threadIdx.x;
    if (b < NBKT) gcursor[b] = b * CAP;
}

// ---- partition: LDS-staged counting sort + 16-lane-group run flush -------
__global__ __launch_bounds__(512) void part1_kernel(const int* __restrict__ src,
                                                    const int* __restrict__ dst,
                                                    int* __restrict__ gcursor,
                                                    int* __restrict__ buf) {
    __shared__ int lhist[NBKT], lbase[NBKT], lstart[NBKT], lcur[NBKT];
    __shared__ int pscan[512];
    __shared__ int lsort[P1_EPB];
    int tid = threadIdx.x;
    size_t base = (size_t)blockIdx.x * P1_EPB;
    for (int b = tid; b < NBKT; b += 512) lhist[b] = 0;
    __syncthreads();
    for (int i = 0; i < 16; i++) {
        size_t e = base + (size_t)i * 512 + tid;
        if (e < N_EDGES) atomicAdd(&lhist[dst[e] >> 7], 1);
    }
    __syncthreads();
    int i0 = tid * 2, i1 = tid * 2 + 1;
    int c0 = (i0 < NBKT) ? lhist[i0] : 0;
    int c1 = (i1 < NBKT) ? lhist[i1] : 0;
    pscan[tid] = c0 + c1;
    __syncthreads();
    #pragma unroll
    for (int o = 1; o < 512; o <<= 1) {
        int t2 = (tid >= o) ? pscan[tid - o] : 0;
        __syncthreads();
        pscan[tid] += t2;
        __syncthreads();
    }
    int prev = (tid > 0) ? pscan[tid - 1] : 0;
    if (i0 < NBKT) { lstart[i0] = prev;      lcur[i0] = prev; }
    if (i1 < NBKT) { lstart[i1] = prev + c0; lcur[i1] = prev + c0; }
    __syncthreads();
    for (int b = tid; b < NBKT; b += 512) {
        int c = lhist[b];
        lbase[b] = c ? atomicAdd(&gcursor[b], c) : 0;
    }
    __syncthreads();
    for (int i = 0; i < 16; i++) {
        size_t e = base + (size_t)i * 512 + tid;
        if (e < N_EDGES) {
            int d = dst[e], s = src[e];
            int b = d >> 7;
            int p = atomicAdd(&lcur[b], 1);
            lsort[p] = ((d & 127) << 17) | s;
        }
    }
    __syncthreads();
    int grp = tid >> 4, gl = tid & 15;
    for (int b = grp; b < NBKT; b += 32) {
        int st = lstart[b], c = lhist[b], gb = lbase[b];
        int lim = (b + 1) * CAP;
        for (int k = gl; k < c; k += 16) {
            int pos = gb + k;
            if (pos < lim)   // capacity guard (P ~ 5e-6 total)
                buf[pos] = lsort[st + k];
        }
    }
}

// ---- part2: per-bucket fine sort in LDS, in place; emits nodeinfo+dinv ---
__global__ __launch_bounds__(512) void part2_kernel(const int* __restrict__ gcursor,
                                                    int* __restrict__ buf,
                                                    int* __restrict__ nodeinfo,
                                                    float* __restrict__ dinv) {
    __shared__ int lcnt[128], lcur[128];
    __shared__ int lsort[CAP];
    int b = blockIdx.x, tid = threadIdx.x;
    int base = b * CAP;
    int end = gcursor[b];
    int count = end - base;
    if (tid < 128) lcnt[tid] = 0;
    __syncthreads();
    for (int i = tid; i < count; i += 512)
        atomicAdd(&lcnt[buf[base + i] >> 17], 1);
    __syncthreads();
    int v = (tid < 128) ? lcnt[tid] : 0;
    #pragma unroll
    for (int o = 1; o < 128; o <<= 1) {
        int t2 = (tid < 128 && tid >= o) ? lcnt[tid - o] : 0;
        __syncthreads();
        if (tid < 128 && tid >= o) lcnt[tid] += t2;
        __syncthreads();
    }
    if (tid < 128) {
        int excl = lcnt[tid] - v;
        lcur[tid] = excl;
        int n = b * 128 + tid;
        if (n < N_NODES) {
            nodeinfo[n] = (v << 23) | (base + excl);
            dinv[n] = rsqrtf((float)v + 1.0f);  // +1 self-loop
        }
    }
    __syncthreads();
    for (int i = tid; i < count; i += 512) {
        int w = buf[base + i];
        int pos = atomicAdd(&lcur[w >> 17], 1);
        lsort[pos] = w & 0x1FFFF;
    }
    __syncthreads();
    for (int i = tid; i < count; i += 512) buf[base + i] = lsort[i];
}

// ---- LayerNorm + W1 + pre-scale by dinv (one wave per node) --------------
__global__ void ln_w1_kernel(const float* __restrict__ x,
                             const float* __restrict__ gamma,
                             const float* __restrict__ beta,
                             const float* __restrict__ W1,
                             const float* __restrict__ dinv,
                             float* __restrict__ g1) {
    int wave = (blockIdx.x * blockDim.x + threadIdx.x) >> 6;
    int lane = threadIdx.x & 63;
    if (wave >= N_NODES) return;
    const float* xr = x + (size_t)wave * 128;
    float x0 = xr[lane], x1 = xr[lane + 64];

    float s1 = x0 + x1;
    float s2 = x0 * x0 + x1 * x1;
    #pragma unroll
    for (int o = 32; o; o >>= 1) {
        s1 += __shfl_xor(s1, o, 64);
        s2 += __shfl_xor(s2, o, 64);
    }
    float mu = s1 * (1.0f / 128.0f);
    float var = s2 * (1.0f / 128.0f) - mu * mu;
    float rstd = rsqrtf(var + 1e-5f);
    float xn0 = (x0 - mu) * rstd * gamma[lane] + beta[lane];
    float xn1 = (x1 - mu) * rstd * gamma[lane + 64] + beta[lane + 64];

    float p[16];
    const float* wr0 = W1 + (size_t)lane * HIDDEN;
    const float* wr1 = W1 + (size_t)(lane + 64) * HIDDEN;
    #pragma unroll
    for (int j = 0; j < 16; j++) p[j] = xn0 * wr0[j] + xn1 * wr1[j];

    // vector-halving butterfly
    float q[8];
    {
        int sel = lane & 1;
        #pragma unroll
        for (int j = 0; j < 8; j++) {
            float mine = sel ? p[j + 8] : p[j];
            float give = sel ? p[j] : p[j + 8];
            q[j] = mine + __shfl_xor(give, 1, 64);
        }
    }
    float r[4];
    {
        int sel = (lane >> 1) & 1;
        #pragma unroll
        for (int j = 0; j < 4; j++) {
            float mine = sel ? q[j + 4] : q[j];
            float give = sel ? q[j] : q[j + 4];
            r[j] = mine + __shfl_xor(give, 2, 64);
        }
    }
    float s[2];
    {
        int sel = (lane >> 2) & 1;
        #pragma unroll
        for (int j = 0; j < 2; j++) {
            float mine = sel ? r[j + 2] : r[j];
            float give = sel ? r[j] : r[j + 2];
            s[j] = mine + __shfl_xor(give, 4, 64);
        }
    }
    float t;
    {
        int sel = (lane >> 3) & 1;
        float mine = sel ? s[1] : s[0];
        float give = sel ? s[0] : s[1];
        t = mine + __shfl_xor(give, 8, 64);
    }
    t += __shfl_xor(t, 16, 64);
    t += __shfl_xor(t, 32, 64);

    if (lane < 16) {
        int f = ((lane & 1) << 3) | ((lane & 2) << 1) |
                ((lane & 4) >> 1) | ((lane & 8) >> 3);  // bitrev4
        g1[(size_t)wave * HIDDEN + f] = t * dinv[wave];
    }
}

// ---- pull conv1 + fused finalize1 (mask-based dropout, 2x unrolled) ------
__global__ __launch_bounds__(256) void pull1_kernel(const int* __restrict__ nodeinfo,
                             const int* __restrict__ sorted_src,
                             const float* __restrict__ g1,
                             const float* __restrict__ dinv,
                             const float* __restrict__ b1,
                             const float* __restrict__ W2,
                             const uint64_t* __restrict__ m1,
                             float* __restrict__ g2) {
    __shared__ float sW2[HIDDEN * HIDDEN];
    if (threadIdx.x < HIDDEN * HIDDEN) sW2[threadIdx.x] = W2[threadIdx.x];
    __syncthreads();
    int n = blockIdx.x * 4 + (threadIdx.x >> 6);   // grid*4 == N_NODES exactly
    int lane = threadIdx.x & 63;
    int c = lane & 3, e4 = lane >> 2;
    int info = nodeinfo[n];
    int start = info & 0x7FFFFF;
    int end = start + (int)((unsigned)info >> 23);

    float4 acc = make_float4(0.f, 0.f, 0.f, 0.f);
    float4 acc2 = make_float4(0.f, 0.f, 0.f, 0.f);
    if (e4 == 0) acc = *(const float4*)&g1[(size_t)n * HIDDEN + c * 4];  // self
    for (int kb = start; kb < end; kb += 128) {
        int e0 = kb + lane, e1 = kb + 64 + lane;
        int idx0 = (e0 < end) ? sorted_src[e0] : -1;
        int idx1 = (e1 < end) ? sorted_src[e1] : -1;
        #pragma unroll
        for (int t = 0; t < 4; t++) {
            int s = __shfl(idx0, t * 16 + e4, 64);
            if (s >= 0) {
                const float4 gv = *(const float4*)&g1[(size_t)s * HIDDEN + c * 4];
                acc.x += gv.x; acc.y += gv.y; acc.z += gv.z; acc.w += gv.w;
            }
        }
        #pragma unroll
        for (int t = 0; t < 4; t++) {
            int s = __shfl(idx1, t * 16 + e4, 64);
            if (s >= 0) {
                const float4 gv = *(const float4*)&g1[(size_t)s * HIDDEN + c * 4];
                acc2.x += gv.x; acc2.y += gv.y; acc2.z += gv.z; acc2.w += gv.w;
            }
        }
    }
    acc.x += acc2.x; acc.y += acc2.y; acc.z += acc2.z; acc.w += acc2.w;
    #pragma unroll
    for (int o = 4; o < 64; o <<= 1) {
        acc.x += __shfl_xor(acc.x, o, 64);
        acc.y += __shfl_xor(acc.y, o, 64);
        acc.z += __shfl_xor(acc.z, o, 64);
        acc.w += __shfl_xor(acc.w, o, 64);
    }
    float di = dinv[n];
    const float4 b1c = *(const float4*)&b1[c * 4];
    // dropout via precomputed keep-bits: node n's 16 bits
    uint32_t mbits = (uint32_t)(m1[n >> 2] >> ((n & 3) * 16));
    const float inv = 1.0f / 0.7f;
    float h[4];
    h[0] = ((mbits >> (c * 4 + 0)) & 1) ? fmaxf(di * acc.x + b1c.x, 0.f) * inv : 0.f;
    h[1] = ((mbits >> (c * 4 + 1)) & 1) ? fmaxf(di * acc.y + b1c.y, 0.f) * inv : 0.f;
    h[2] = ((mbits >> (c * 4 + 2)) & 1) ? fmaxf(di * acc.z + b1c.z, 0.f) * inv : 0.f;
    h[3] = ((mbits >> (c * 4 + 3)) & 1) ? fmaxf(di * acc.w + b1c.w, 0.f) * inv : 0.f;
    float4 o4 = make_float4(0.f, 0.f, 0.f, 0.f);
    #pragma unroll
    for (int i = 0; i < HIDDEN; i++) {
        float hi = __shfl(h[i & 3], i >> 2, 64);
        const float4 w = *(const float4*)&sW2[i * HIDDEN + c * 4];
        o4.x += hi * w.x; o4.y += hi * w.y; o4.z += hi * w.z; o4.w += hi * w.w;
    }
    if (e4 == 0)
        *(float4*)&g2[(size_t)n * HIDDEN + c * 4] =
            make_float4(o4.x * di, o4.y * di, o4.z * di, o4.w * di);
}

// ---- pull conv2 + fused finalize2 ----------------------------------------
__global__ __launch_bounds__(256) void pull2_kernel(const int* __restrict__ nodeinfo,
                             const int* __restrict__ sorted_src,
                             const float* __restrict__ g2,
                             const float* __restrict__ dinv,
                             const float* __restrict__ b2,
                             const uint64_t* __restrict__ m2,
                             float* __restrict__ out) {
    int n = blockIdx.x * 4 + (threadIdx.x >> 6);
    int lane = threadIdx.x & 63;
    int c = lane & 3, e4 = lane >> 2;
    int info = nodeinfo[n];
    int start = info & 0x7FFFFF;
    int end = start + (int)((unsigned)info >> 23);

    float4 acc = make_float4(0.f, 0.f, 0.f, 0.f);
    float4 acc2 = make_float4(0.f, 0.f, 0.f, 0.f);
    if (e4 == 0) acc = *(const float4*)&g2[(size_t)n * HIDDEN + c * 4];
    for (int kb = start; kb < end; kb += 128) {
        int e0 = kb + lane, e1 = kb + 64 + lane;
        int idx0 = (e0 < end) ? sorted_src[e0] : -1;
        int idx1 = (e1 < end) ? sorted_src[e1] : -1;
        #pragma unroll
        for (int t = 0; t < 4; t++) {
            int s = __shfl(idx0, t * 16 + e4, 64);
            if (s >= 0) {
                const float4 gv = *(const float4*)&g2[(size_t)s * HIDDEN + c * 4];
                acc.x += gv.x; acc.y += gv.y; acc.z += gv.z; acc.w += gv.w;
            }
        }
        #pragma unroll
        for (int t = 0; t < 4; t++) {
            int s = __shfl(idx1, t * 16 + e4, 64);
            if (s >= 0) {
                const float4 gv = *(const float4*)&g2[(size_t)s * HIDDEN + c * 4];
                acc2.x += gv.x; acc2.y += gv.y; acc2.z += gv.z; acc2.w += gv.w;
            }
        }
    }
    acc.x += acc2.x; acc.y += acc2.y; acc.z += acc2.z; acc.w += acc2.w;
    #pragma unroll
    for (int o = 4; o < 64; o <<= 1) {
        acc.x += __shfl_xor(acc.x, o, 64);
        acc.y += __shfl_xor(acc.y, o, 64);
        acc.z += __shfl_xor(acc.z, o, 64);
        acc.w += __shfl_xor(acc.w, o, 64);
    }
    if (e4 == 0) {
        float di = dinv[n];
        const float4 b2c = *(const float4*)&b2[c * 4];
        uint32_t mbits = (uint32_t)(m2[n >> 2] >> ((n & 3) * 16));
        const float inv = 1.0f / 0.7f;
        float4 r;
        r.x = ((mbits >> (c * 4 + 0)) & 1) ? fmaxf(di * acc.x + b2c.x, 0.f) * inv : 0.f;
        r.y = ((mbits >> (c * 4 + 1)) & 1) ? fmaxf(di * acc.y + b2c.y, 0.f) * inv : 0.f;
        r.z = ((mbits >> (c * 4 + 2)) & 1) ? fmaxf(di * acc.z + b2c.z, 0.f) * inv : 0.f;
        r.w = ((mbits >> (c * 4 + 3)) & 1) ? fmaxf(di * acc.w + b2c.w, 0.f) * inv : 0.f;
        *(float4*)&out[(size_t)n * HIDDEN + c * 4] = r;
    }
}

extern "C" void kernel_launch(void* const* d_in, const int* in_sizes, int n_in,
                              void* d_out, int out_size, void* d_ws, size_t ws_size,
                              hipStream_t stream) {
    const float* x     = (const float*)d_in[0];
    const int*   ei    = (const int*)d_in[1];
    const float* gamma = (const float*)d_in[2];
    const float* beta  = (const float*)d_in[3];
    const float* W1    = (const float*)d_in[4];
    const float* b1    = (const float*)d_in[5];
    const float* W2    = (const float*)d_in[6];
    const float* b2    = (const float*)d_in[7];
    float* out = (float*)d_out;
    const int* src = ei;
    const int* dst = ei + N_EDGES;

    uint32_t dk1_0, dk1_1, dk2_0, dk2_1;
    threefry2x32(0u, 42u, 0u, 0u, dk1_0, dk1_1);
    threefry2x32(0u, 42u, 0u, 1u, dk2_0, dk2_1);

    // ws layout (4B elems): gcursor[1024] | nodeinfo[100k] | dinv[100k] |
    // buf[NBKT*CAP] | g1[1.6M] | g2[1.6M] | m1[25k ull] | m2[25k ull] (~41.4MB)
    int*      gcursor  = (int*)d_ws;
    int*      nodeinfo = gcursor + 1024;
    float*    dinv     = (float*)(nodeinfo + N_NODES);
    int*      buf      = (int*)(dinv + N_NODES);
    float*    g1       = (float*)(buf + (size_t)NBKT * CAP);
    float*    g2       = g1 + (size_t)N_NODES * HIDDEN;
    uint64_t* m1       = (uint64_t*)(g2 + (size_t)N_NODES * HIDDEN);
    uint64_t* m2       = m1 + (NMASK >> 6);

    const int NB_W  = N_NODES / 4;                     // 25000 (4 waves/block)
    const int NB_P1 = (N_EDGES + P1_EPB - 1) / P1_EPB; // 782

    initcur_kernel<<<1, 1024, 0, stream>>>(gcursor);
    dropmask_kernel<<<(2 * NMASK) / 256, 256, 0, stream>>>(m1, m2,
                                                           dk1_0, dk1_1,
                                                           dk2_0, dk2_1);
    part1_kernel<<<NB_P1, 512, 0, stream>>>(src, dst, gcursor, buf);
    part2_kernel<<<NBKT, 512, 0, stream>>>(gcursor, buf, nodeinfo, dinv);
    ln_w1_kernel<<<NB_W, 256, 0, stream>>>(x, gamma, beta, W1, dinv, g1);
    pull1_kernel<<<NB_W, 256, 0, stream>>>(nodeinfo, buf, g1,
                                           dinv, b1, W2, m1, g2);
    pull2_kernel<<<NB_W, 256, 0, stream>>>(nodeinfo, buf, g2,
                                           dinv, b2, m2, out);
}